// Round 8
// baseline (3907.606 us; speedup 1.0000x reference)
//
#include <hip/hip_runtime.h>
#include <stdint.h>

#define NN 100000
#define NE 3200000
#define NNZT (NE + NN)
#define DIM 256
#define WCOLS 2048

typedef __bf16 v8bf __attribute__((ext_vector_type(8)));
typedef float f32x4 __attribute__((ext_vector_type(4)));
typedef float f32x2 __attribute__((ext_vector_type(2)));

__device__ __forceinline__ unsigned f2bfu(float f){
  unsigned u = __builtin_bit_cast(unsigned, f);
  return (u + 0x7FFFu + ((u >> 16) & 1u)) >> 16;
}
__device__ __forceinline__ float bflo(unsigned u){ return __builtin_bit_cast(float, u << 16); }
__device__ __forceinline__ float bfhi(unsigned u){ return __builtin_bit_cast(float, u & 0xFFFF0000u); }
__device__ __forceinline__ float lrelu(float x){ return fmaxf(x, 0.2f * x); }
__device__ __forceinline__ int imin(int a, int b){ return a < b ? a : b; }

// fp8 dword -> 2 packed bf16 dwords (4 elems)
__device__ __forceinline__ void fp8dw_to_bf16x4(int dw, int& o0, int& o1){
  f32x2 lo = __builtin_amdgcn_cvt_pk_f32_fp8(dw, false);
  f32x2 hi = __builtin_amdgcn_cvt_pk_f32_fp8(dw, true);
  o0 = (int)(f2bfu(lo[0]) | (f2bfu(lo[1]) << 16));
  o1 = (int)(f2bfu(hi[0]) | (f2bfu(hi[1]) << 16));
}

// 8 bf16 (int4) scaled-accumulate into 8 fp32
__device__ __forceinline__ void fma8(int4 v, float w, float* a){
  unsigned ux = (unsigned)v.x, uy = (unsigned)v.y, uz = (unsigned)v.z, uw = (unsigned)v.w;
  a[0] += w * bflo(ux); a[1] += w * bfhi(ux);
  a[2] += w * bflo(uy); a[3] += w * bfhi(uy);
  a[4] += w * bflo(uz); a[5] += w * bfhi(uz);
  a[6] += w * bflo(uw); a[7] += w * bfhi(uw);
}

// ---- cast x fp32 -> bf16 (4 elems/thread) ----
__global__ void k_cast_x(const float* __restrict__ x, unsigned short* __restrict__ xb){
  int t = blockIdx.x * 256 + threadIdx.x;           // 6.4M threads exact
  float4 v = ((const float4*)x)[t];
  uint2 o;
  o.x = f2bfu(v.x) | (f2bfu(v.y) << 16);
  o.y = f2bfu(v.z) | (f2bfu(v.w) << 16);
  ((uint2*)xb)[t] = o;
}

// ---- WaggT[j][h*256+d] = W[d][h*256+j] / 8  (bf16, [256][2048]) ----
__global__ void k_make_waggt(const float* __restrict__ W, unsigned short* __restrict__ bt){
  int t = blockIdx.x * 256 + threadIdx.x;           // 524288
  int j = t >> 11, c = t & 2047;
  int h = c >> 8, d = c & 255;
  bt[t] = (unsigned short)f2bfu(W[(size_t)d * WCOLS + h * 256 + j] * 0.125f);
}

// ---- Vt[h][k] = sum_d W[k][h*256+d]*a_s[h][d]; Vt[8+h][k] same with a_d ----
__global__ void k_make_vt(const float* __restrict__ W, const float* __restrict__ as_,
                          const float* __restrict__ ad_, unsigned short* __restrict__ vt){
  int h = blockIdx.x, k = threadIdx.x;              // 8 x 256
  const float* wr = W + (size_t)k * WCOLS + h * 256;
  const float* a1 = as_ + h * 256;
  const float* a2 = ad_ + h * 256;
  float ss = 0.f, sd = 0.f;
  for (int d = 0; d < 256; ++d){ float wv = wr[d]; ss += wv * a1[d]; sd += wv * a2[d]; }
  vt[h * 256 + k] = (unsigned short)f2bfu(ss);
  vt[(8 + h) * 256 + k] = (unsigned short)f2bfu(sd);
}

// ---- CSR build (structure identical to the round-2/7 PASSING kernels) ----
__global__ void k_zero_col(int* __restrict__ col){
  int t = blockIdx.x * 256 + threadIdx.x;
  if (t < NNZT) col[t] = 0;
}
__global__ void k_deg_init(int* __restrict__ deg){
  int t = blockIdx.x * 256 + threadIdx.x;
  if (t < NN) deg[t] = 1;                            // self-loop
}
__global__ void k_hist(const int* __restrict__ ei, int* __restrict__ deg){
  int t = blockIdx.x * 256 + threadIdx.x;            // NE threads exact
  int d = ei[NE + t];
  if ((unsigned)d < NN) atomicAdd(&deg[d], 1);
}
// chunked scan; deg and cur are DISTINCT buffers; cur not restrict-qualified
__global__ void __launch_bounds__(1024) k_scan(const int* __restrict__ deg,
                                               int* __restrict__ rp, int* cur){
  __shared__ int ps[1024];
  int t = threadIdx.x;
  int lo = t * 98;
  int hi = lo + 98; if (hi > NN) hi = NN; if (lo > NN) lo = NN;
  int s = 0;
  for (int i = lo; i < hi; ++i) s += deg[i];
  ps[t] = s;
  __syncthreads();
  if (t == 0){
    int run = 0;
    for (int i = 0; i < 1024; ++i){ int v = ps[i]; ps[i] = run; run += v; }
    rp[NN] = run;
  }
  __syncthreads();
  int run = ps[t];
  for (int i = lo; i < hi; ++i){
    int dv = deg[i];
    rp[i] = run; cur[i] = run;
    run += dv;
  }
}
__global__ void k_fill_self(int* __restrict__ cur, int* __restrict__ col){
  int t = blockIdx.x * 256 + threadIdx.x;
  if (t < NN){
    int s = atomicAdd(&cur[t], 1);
    if ((unsigned)s < NNZT) col[s] = t;
  }
}
__global__ void k_fill_edge(const int* __restrict__ ei, int* __restrict__ cur, int* __restrict__ col){
  int t = blockIdx.x * 256 + threadIdx.x;
  int s = ei[t], d = ei[NE + t];
  if ((unsigned)d >= NN) return;                     // matches k_hist guard
  if ((unsigned)s >= NN) s = d;
  int slot = atomicAdd(&cur[d], 1);
  if ((unsigned)slot < NNZT) col[slot] = s;
}

// ---- per-layer P/Q: out = relu?(val*P + Q) ----
__global__ void k_pq(const float* g, const float* be, const float* m, const float* v,
                     const float* __restrict__ b, int has_bn,
                     float* __restrict__ P, float* __restrict__ Q){
  int j = threadIdx.x;
  if (has_bn){
    float A = g[j] * rsqrtf(v[j] + 1e-5f);
    P[j] = A; Q[j] = (b[j] - m[j]) * A + be[j];
  } else {
    P[j] = 1.0f; Q[j] = b[j];
  }
}

// ---- alpha: [als|ald] = xb @ Vt^T via one MFMA wave per 16 nodes ----
__global__ void __launch_bounds__(256) k_alpha(const unsigned short* __restrict__ xb,
    const unsigned short* __restrict__ vt,
    float* __restrict__ als, float* __restrict__ ald){
  int tile = blockIdx.x * 4 + (threadIdx.x >> 6);
  if (tile >= NN / 16) return;                       // 6250 exact
  int lane = threadIdx.x & 63;
  int ri = lane & 15, kg = lane >> 4;
  size_t m0 = (size_t)tile * 16;
  const int4* A = (const int4*)(xb + m0 * DIM);      // row stride 32 int4
  const int4* B = (const int4*)vt;                   // [16][256] bf16
  f32x4 acc = {0.f, 0.f, 0.f, 0.f};
  #pragma unroll
  for (int ks = 0; ks < 8; ++ks){
    v8bf av = __builtin_bit_cast(v8bf, A[ri * 32 + ks * 4 + kg]);
    v8bf bv = __builtin_bit_cast(v8bf, B[ri * 32 + ks * 4 + kg]);
    acc = __builtin_amdgcn_mfma_f32_16x16x32_bf16(av, bv, acc, 0, 0, 0);
  }
  #pragma unroll
  for (int r = 0; r < 4; ++r){
    size_t m = m0 + kg * 4 + r;
    if (ri < 8) als[m * 8 + ri] = acc[r];
    else        ald[m * 8 + (ri - 8)] = acc[r];
  }
}

// ---- aggregation over x: z8[n, h*256+d] = fp8( (1/den_h) * sum_e w_he * x[src_e, d] )
// one wave per node; lane = (h = lane&7, dg = lane>>3 owning dims dg*32 .. +31)
// 2-edge software pipeline: 8 independent x-int4 loads per iteration for MLP.
__global__ void __launch_bounds__(256) k_aggregate_x(const unsigned short* __restrict__ xb,
    const float* __restrict__ als, const float* __restrict__ ald,
    const int* __restrict__ rp, const int* __restrict__ col,
    unsigned char* __restrict__ z8){
  int n = blockIdx.x * 4 + (threadIdx.x >> 6);       // 100000 exact
  int lane = threadIdx.x & 63;
  int h = lane & 7, dg = lane >> 3;
  int start = rp[n], end = rp[n + 1];
  if (start < 0) start = 0;
  if (end > NNZT) end = NNZT;
  if (end < start) end = start;
  float aldv = ald[(size_t)n * 8 + h];
  const unsigned short* xbase = xb + dg * 32;

  float den = 0.f;
  float acc[32];
  #pragma unroll
  for (int j = 0; j < 32; ++j) acc[j] = 0.f;

  int e = start;
  if ((end - start) & 1){                            // peel one edge if odd count
    int src = col[e];
    if ((unsigned)src >= NN) src = n;
    const int4* xp = (const int4*)(xbase + (size_t)src * DIM);
    int4 u0 = xp[0], u1 = xp[1], u2 = xp[2], u3 = xp[3];
    float w = __expf(lrelu(als[(size_t)src * 8 + h] + aldv));
    den += w;
    fma8(u0, w, acc + 0);  fma8(u1, w, acc + 8);
    fma8(u2, w, acc + 16); fma8(u3, w, acc + 24);
    ++e;
  }
  for (; e < end; e += 2){
    int s0 = col[e], s1 = col[e + 1];
    if ((unsigned)s0 >= NN) s0 = n;
    if ((unsigned)s1 >= NN) s1 = n;
    const int4* xp0 = (const int4*)(xbase + (size_t)s0 * DIM);
    const int4* xp1 = (const int4*)(xbase + (size_t)s1 * DIM);
    int4 u0 = xp0[0], u1 = xp0[1], u2 = xp0[2], u3 = xp0[3];
    int4 t0 = xp1[0], t1 = xp1[1], t2 = xp1[2], t3 = xp1[3];
    float a0 = als[(size_t)s0 * 8 + h];
    float a1 = als[(size_t)s1 * 8 + h];
    float w0 = __expf(lrelu(a0 + aldv));
    float w1 = __expf(lrelu(a1 + aldv));
    den += w0 + w1;
    fma8(u0, w0, acc + 0);  fma8(u1, w0, acc + 8);
    fma8(u2, w0, acc + 16); fma8(u3, w0, acc + 24);
    fma8(t0, w1, acc + 0);  fma8(t1, w1, acc + 8);
    fma8(t2, w1, acc + 16); fma8(t3, w1, acc + 24);
  }
  float r = 1.0f / den;
  unsigned pk[8];
  #pragma unroll
  for (int q = 0; q < 8; ++q){
    int w0 = __builtin_amdgcn_cvt_pk_fp8_f32(acc[q*4+0]*r, acc[q*4+1]*r, 0, false);
    pk[q] = (unsigned)__builtin_amdgcn_cvt_pk_fp8_f32(acc[q*4+2]*r, acc[q*4+3]*r, w0, true);
  }
  unsigned char* zp = z8 + (size_t)n * WCOLS + h * 256 + dg * 32;
  ((uint4*)zp)[0] = make_uint4(pk[0], pk[1], pk[2], pk[3]);
  ((uint4*)zp)[1] = make_uint4(pk[4], pk[5], pk[6], pk[7]);
}

// ---- big GEMM: out[n,j] = sum_k z[n,k] * bt[j,k]; epilogue P/Q (+relu, bf16) ----
// 512 threads = 8 waves (2 row x 4 col), BM=128, BN=256, BK=64.
// Stage-ahead 2-phase: issue t+1 global loads right after the first barrier
// so they fly during the MFMA phase (T3 minimum-2-phase pattern).
// A staged fp8 -> bf16 in registers, ds_write_b128 with XOR swizzle
// (physical 16B-block = logical_blk ^ (row & 7)) on BOTH write and read.
__global__ void __launch_bounds__(512) k_gemm2(const unsigned char* __restrict__ z8,
    const unsigned short* __restrict__ bt,
    const float* __restrict__ Pb, const float* __restrict__ Qb,
    unsigned short* __restrict__ xout, float* __restrict__ fout, int last){
  __shared__ __align__(16) unsigned short sA[128 * 64];   // 16 KB
  __shared__ __align__(16) unsigned short sB[256 * 64];   // 32 KB
  int tid = threadIdx.x;
  int w = tid >> 6, lane = tid & 63;
  int wr = w >> 2, wc = w & 3;
  int ri = lane & 15, kg = lane >> 4;
  int m0 = blockIdx.x * 128;

  // A staging: row = tid>>2 (0..127), kq = tid&3 -> 16 fp8 bytes
  int rowA = tid >> 2, kqA = tid & 3;
  int rA = imin(m0 + rowA, NN - 1);
  const unsigned char* zrow = z8 + (size_t)rA * WCOLS + kqA * 16;
  int sAoff0 = rowA * 64 + (((kqA * 2)     ^ (rowA & 7)) * 8);
  int sAoff1 = rowA * 64 + (((kqA * 2 + 1) ^ (rowA & 7)) * 8);

  // B staging: 4 units; row = u>>3 (0..255), lb = u&7 (16B = 8 bf16)
  int rB[4], sBoff[4];
  #pragma unroll
  for (int p = 0; p < 4; ++p){
    int u = tid + p * 512;
    int row = u >> 3, lb = u & 7;
    rB[p] = row;
    sBoff[p] = row * 64 + ((lb ^ (row & 7)) * 8);
  }
  int lbB = tid & 7;

  f32x4 acc[4][4];
  #pragma unroll
  for (int i = 0; i < 4; ++i)
    #pragma unroll
    for (int j = 0; j < 4; ++j) acc[i][j] = (f32x4){0.f, 0.f, 0.f, 0.f};

  // prologue: loads for t=0
  uint4 raw = *(const uint4*)(zrow);
  int4 vb[4];
  #pragma unroll
  for (int p = 0; p < 4; ++p)
    vb[p] = *(const int4*)(bt + (size_t)rB[p] * WCOLS + lbB * 8);

  for (int t = 0; t < 32; ++t){
    // write LDS from staged registers
    int4 cl, ch;
    fp8dw_to_bf16x4((int)raw.x, cl.x, cl.y);
    fp8dw_to_bf16x4((int)raw.y, cl.z, cl.w);
    fp8dw_to_bf16x4((int)raw.z, ch.x, ch.y);
    fp8dw_to_bf16x4((int)raw.w, ch.z, ch.w);
    *(int4*)(sA + sAoff0) = cl;
    *(int4*)(sA + sAoff1) = ch;
    #pragma unroll
    for (int p = 0; p < 4; ++p) *(int4*)(sB + sBoff[p]) = vb[p];
    __syncthreads();

    // issue next-tile global loads; they fly during the MFMA phase
    if (t < 31){
      int kn = (t + 1) * 64;
      raw = *(const uint4*)(zrow + kn);
      #pragma unroll
      for (int p = 0; p < 4; ++p)
        vb[p] = *(const int4*)(bt + (size_t)rB[p] * WCOLS + kn + lbB * 8);
    }

    // MFMA phase
    #pragma unroll
    for (int ks = 0; ks < 2; ++ks){
      v8bf a[4], b[4];
      #pragma unroll
      for (int ai = 0; ai < 4; ++ai){
        int r = wr * 64 + ai * 16 + ri;
        int pb = (ks * 4 + kg) ^ (r & 7);
        a[ai] = *(const v8bf*)((const unsigned char*)sA + r * 128 + pb * 16);
      }
      #pragma unroll
      for (int bj = 0; bj < 4; ++bj){
        int r = wc * 64 + bj * 16 + ri;
        int pb = (ks * 4 + kg) ^ (r & 7);
        b[bj] = *(const v8bf*)((const unsigned char*)sB + r * 128 + pb * 16);
      }
      #pragma unroll
      for (int ai = 0; ai < 4; ++ai)
        #pragma unroll
        for (int bj = 0; bj < 4; ++bj)
          acc[ai][bj] = __builtin_amdgcn_mfma_f32_16x16x32_bf16(a[ai], b[bj], acc[ai][bj], 0, 0, 0);
    }
    __syncthreads();
  }

  // epilogue: C[m0 + wr*64 + ai*16 + kg*4 + r][wc*64 + bj*16 + ri]
  #pragma unroll
  for (int bj = 0; bj < 4; ++bj){
    int colj = wc * 64 + bj * 16 + ri;
    float p = Pb[colj], q = Qb[colj];
    #pragma unroll
    for (int ai = 0; ai < 4; ++ai){
      #pragma unroll
      for (int r = 0; r < 4; ++r){
        int row = m0 + wr * 64 + ai * 16 + kg * 4 + r;
        if (row < NN){
          float v = acc[ai][bj][r] * p + q;
          if (!last){
            v = fmaxf(v, 0.f);
            xout[(size_t)row * DIM + colj] = (unsigned short)f2bfu(v);
          } else {
            fout[(size_t)row * DIM + colj] = v;
          }
        }
      }
    }
  }
}

// ---- doc GEMM: [64,3072]@[3072,256] fp32, one block per row ----
__global__ void __launch_bounds__(256) k_doc(const float* __restrict__ dd,
    const float* __restrict__ dw, const float* __restrict__ db, float* __restrict__ out){
  int r = blockIdx.x;                 // 64 rows
  int j = threadIdx.x;                // 256 cols
  const float* drow = dd + (size_t)r * 3072;
  float acc = db[j];
  #pragma unroll 4
  for (int k = 0; k < 3072; ++k)
    acc = fmaf(drow[k], dw[(size_t)k * 256 + j], acc);
  out[(size_t)NN * DIM + (size_t)r * 256 + j] = acc;
}

extern "C" void kernel_launch(void* const* d_in, const int* in_sizes, int n_in,
                              void* d_out, int out_size, void* d_ws, size_t ws_size,
                              hipStream_t stream) {
  (void)in_sizes; (void)n_in; (void)out_size; (void)ws_size;
  const float* x      = (const float*)d_in[0];
  const int*   ei     = (const int*)d_in[1];
  const float* doc    = (const float*)d_in[2];
  const float* W[3]   = {(const float*)d_in[3], (const float*)d_in[7], (const float*)d_in[11]};
  const float* as_[3] = {(const float*)d_in[4], (const float*)d_in[8], (const float*)d_in[12]};
  const float* ad_[3] = {(const float*)d_in[5], (const float*)d_in[9], (const float*)d_in[13]};
  const float* b_[3]  = {(const float*)d_in[6], (const float*)d_in[10], (const float*)d_in[14]};
  const float* bng[2] = {(const float*)d_in[15], (const float*)d_in[19]};
  const float* bnb[2] = {(const float*)d_in[16], (const float*)d_in[20]};
  const float* bnm[2] = {(const float*)d_in[17], (const float*)d_in[21]};
  const float* bnv[2] = {(const float*)d_in[18], (const float*)d_in[22]};
  const float* docW   = (const float*)d_in[23];
  const float* docB   = (const float*)d_in[24];
  float* out = (float*)d_out;

  char* ws = (char*)d_ws;
  // EXACT round-2/round-7-proven layout: total footprint 279,947,840 bytes.
  unsigned short* xb   = (unsigned short*)(ws + 0);            //  51,200,000
  unsigned char*  z8   = (unsigned char*)(ws + 51200000);      // 204,800,000
  float* als           = (float*)(ws + 256000000);             //   3,200,000
  float* ald           = (float*)(ws + 259200000);             //   3,200,000
  unsigned short* bt   = (unsigned short*)(ws + 262400000);    //   3,145,728 (3 x 1 MiB)
  int* rp              = (int*)(ws + 265545728);               //     400,064
  int* deg             = (int*)(ws + 265945792);               //     400,000
  int* cur             = (int*)(ws + 266345792);               //     400,000
  int* colb            = (int*)(ws + 266745792);               //  13,200,000
  float* Pb            = (float*)(ws + 279945792);             //       1,024
  float* Qb            = (float*)(ws + 279946816);             //       1,024 -> end 279,947,840
  // vt (24,576 B) aliases cur; written only AFTER cur's last use (k_fill_edge)
  unsigned short* vt   = (unsigned short*)(ws + 266345792);

  // input prep
  k_cast_x<<<25000, 256, 0, stream>>>(x, xb);
  for (int L = 0; L < 3; ++L)
    k_make_waggt<<<2048, 256, 0, stream>>>(W[L], bt + (size_t)L * 524288);

  // CSR (shared by all 3 layers); deg/cur strictly distinct buffers
  k_zero_col<<<12891, 256, 0, stream>>>(colb);
  k_deg_init<<<391, 256, 0, stream>>>(deg);
  k_hist<<<12500, 256, 0, stream>>>(ei, deg);
  k_scan<<<1, 1024, 0, stream>>>(deg, rp, cur);
  k_fill_self<<<391, 256, 0, stream>>>(cur, colb);
  k_fill_edge<<<12500, 256, 0, stream>>>(ei, cur, colb);

  // vt after CSR build (reuses cur's storage; cur is never used again)
  for (int L = 0; L < 3; ++L)
    k_make_vt<<<8, 256, 0, stream>>>(W[L], as_[L], ad_[L], vt + (size_t)L * 4096);

  // layers
  for (int L = 0; L < 3; ++L){
    int has_bn = (L < 2) ? 1 : 0;
    k_pq<<<1, 256, 0, stream>>>(has_bn ? bng[L] : nullptr, has_bn ? bnb[L] : nullptr,
                                has_bn ? bnm[L] : nullptr, has_bn ? bnv[L] : nullptr,
                                b_[L], has_bn, Pb, Qb);
    k_alpha<<<1563, 256, 0, stream>>>(xb, vt + (size_t)L * 4096, als, ald);
    k_aggregate_x<<<25000, 256, 0, stream>>>(xb, als, ald, rp, colb, z8);
    k_gemm2<<<782, 512, 0, stream>>>(z8, bt + (size_t)L * 524288, Pb, Qb,
                                     xb, out, (L == 2) ? 1 : 0);
  }

  // doc branch
  k_doc<<<64, 256, 0, stream>>>(doc, docW, docB, out);
}

// Round 10
// 3356.773 us; speedup vs baseline: 1.1641x; 1.1641x over previous
//
#include <hip/hip_runtime.h>
#include <stdint.h>

#define NN 100000
#define NE 3200000
#define NNZT (NE + NN)
#define DIM 256
#define WCOLS 2048

typedef __bf16 v8bf __attribute__((ext_vector_type(8)));
typedef float f32x4 __attribute__((ext_vector_type(4)));
typedef float f32x2 __attribute__((ext_vector_type(2)));

__device__ __forceinline__ unsigned f2bfu(float f){
  unsigned u = __builtin_bit_cast(unsigned, f);
  return (u + 0x7FFFu + ((u >> 16) & 1u)) >> 16;
}
__device__ __forceinline__ float lrelu(float x){ return fmaxf(x, 0.2f * x); }
__device__ __forceinline__ int imin(int a, int b){ return a < b ? a : b; }
__device__ __forceinline__ unsigned char f2fp8(float f){
  return (unsigned char)(__builtin_amdgcn_cvt_pk_fp8_f32(f, f, 0, false) & 0xff);
}
// packed dual-FP32 FMA: d = a*b + c on 2-wide f32 (VGPR pairs)
__device__ __forceinline__ f32x2 pkfma(f32x2 a, f32x2 b, f32x2 c){
  f32x2 d;
  asm("v_pk_fma_f32 %0, %1, %2, %3" : "=v"(d) : "v"(a), "v"(b), "v"(c));
  return d;
}
// fp8 dword -> 2 packed bf16 dwords (4 elems) for LDS staging in gemm2
__device__ __forceinline__ void fp8dw_to_bf16x4(int dw, int& o0, int& o1){
  f32x2 lo = __builtin_amdgcn_cvt_pk_f32_fp8(dw, false);
  f32x2 hi = __builtin_amdgcn_cvt_pk_f32_fp8(dw, true);
  o0 = (int)(f2bfu(lo[0]) | (f2bfu(lo[1]) << 16));
  o1 = (int)(f2bfu(hi[0]) | (f2bfu(hi[1]) << 16));
}
// 32 fp8 bytes (two int4) scaled-accumulate into 16 f32x2 accumulators
__device__ __forceinline__ void acc32fp8(int4 u0, int4 u1, f32x2 w2, f32x2* acc2){
  int dws[8] = {u0.x, u0.y, u0.z, u0.w, u1.x, u1.y, u1.z, u1.w};
  #pragma unroll
  for (int m = 0; m < 8; ++m){
    f32x2 lo = __builtin_amdgcn_cvt_pk_f32_fp8(dws[m], false);
    f32x2 hi = __builtin_amdgcn_cvt_pk_f32_fp8(dws[m], true);
    acc2[2*m]   = pkfma(lo, w2, acc2[2*m]);
    acc2[2*m+1] = pkfma(hi, w2, acc2[2*m+1]);
  }
}

// ---- cast x fp32 -> fp8 (4 elems/thread) ----
__global__ void k_cast_x8(const float* __restrict__ x, unsigned char* __restrict__ x8){
  int t = blockIdx.x * 256 + threadIdx.x;           // 6.4M threads exact
  float4 v = ((const float4*)x)[t];
  int lo = __builtin_amdgcn_cvt_pk_fp8_f32(v.x, v.y, 0, false);
  int both = __builtin_amdgcn_cvt_pk_fp8_f32(v.z, v.w, lo, true);
  ((int*)x8)[t] = both;
}

// ---- WaggT[j][h*256+d] = W[d][h*256+j] / 8  (bf16, [256][2048]) ----
__global__ void k_make_waggt(const float* __restrict__ W, unsigned short* __restrict__ bt){
  int t = blockIdx.x * 256 + threadIdx.x;           // 524288
  int j = t >> 11, c = t & 2047;
  int h = c >> 8, d = c & 255;
  bt[t] = (unsigned short)f2bfu(W[(size_t)d * WCOLS + h * 256 + j] * 0.125f);
}

// ---- Vtf[h][k] = sum_d W[k][h*256+d]*a_s[h][d]; Vtf[8+h][k] same with a_d (fp32) ----
__global__ void k_make_vtf(const float* __restrict__ W, const float* __restrict__ as_,
                           const float* __restrict__ ad_, float* __restrict__ vtf){
  int h = blockIdx.x, k = threadIdx.x;              // 8 x 256
  const float* wr = W + (size_t)k * WCOLS + h * 256;
  const float* a1 = as_ + h * 256;
  const float* a2 = ad_ + h * 256;
  float ss = 0.f, sd = 0.f;
  for (int d = 0; d < 256; ++d){ float wv = wr[d]; ss += wv * a1[d]; sd += wv * a2[d]; }
  vtf[h * 256 + k] = ss;
  vtf[(8 + h) * 256 + k] = sd;
}

// ---- CSR build (structure identical to the round-2/7 PASSING kernels) ----
__global__ void k_zero_col(int* __restrict__ col){
  int t = blockIdx.x * 256 + threadIdx.x;
  if (t < NNZT) col[t] = 0;
}
__global__ void k_deg_init(int* __restrict__ deg){
  int t = blockIdx.x * 256 + threadIdx.x;
  if (t < NN) deg[t] = 1;                            // self-loop
}
__global__ void k_hist(const int* __restrict__ ei, int* __restrict__ deg){
  int t = blockIdx.x * 256 + threadIdx.x;            // NE threads exact
  int d = ei[NE + t];
  if ((unsigned)d < NN) atomicAdd(&deg[d], 1);
}
__global__ void __launch_bounds__(1024) k_scan(const int* __restrict__ deg,
                                               int* __restrict__ rp, int* cur){
  __shared__ int ps[1024];
  int t = threadIdx.x;
  int lo = t * 98;
  int hi = lo + 98; if (hi > NN) hi = NN; if (lo > NN) lo = NN;
  int s = 0;
  for (int i = lo; i < hi; ++i) s += deg[i];
  ps[t] = s;
  __syncthreads();
  if (t == 0){
    int run = 0;
    for (int i = 0; i < 1024; ++i){ int v = ps[i]; ps[i] = run; run += v; }
    rp[NN] = run;
  }
  __syncthreads();
  int run = ps[t];
  for (int i = lo; i < hi; ++i){
    int dv = deg[i];
    rp[i] = run; cur[i] = run;
    run += dv;
  }
}
__global__ void k_fill_self(int* __restrict__ cur, int* __restrict__ col){
  int t = blockIdx.x * 256 + threadIdx.x;
  if (t < NN){
    int s = atomicAdd(&cur[t], 1);
    if ((unsigned)s < NNZT) col[s] = t;
  }
}
__global__ void k_fill_edge(const int* __restrict__ ei, int* __restrict__ cur, int* __restrict__ col){
  int t = blockIdx.x * 256 + threadIdx.x;
  int s = ei[t], d = ei[NE + t];
  if ((unsigned)d >= NN) return;                     // matches k_hist guard
  if ((unsigned)s >= NN) s = d;
  int slot = atomicAdd(&cur[d], 1);
  if ((unsigned)slot < NNZT) col[slot] = s;
}

// ---- per-layer P/Q: out = relu?(val*P + Q) ----
__global__ void k_pq(const float* g, const float* be, const float* m, const float* v,
                     const float* __restrict__ b, int has_bn,
                     float* __restrict__ P, float* __restrict__ Q){
  int j = threadIdx.x;
  if (has_bn){
    float A = g[j] * rsqrtf(v[j] + 1e-5f);
    P[j] = A; Q[j] = (b[j] - m[j]) * A + be[j];
  } else {
    P[j] = 1.0f; Q[j] = b[j];
  }
}

// ---- alpha (vector): [als|ald][n,j] = sum_k x8[n,k] * vtf[j][k] ----
// one wave per node; lane = (j = lane&15 output, q = lane>>4 dim-quarter of 64)
__global__ void __launch_bounds__(256) k_alpha_v(const unsigned char* __restrict__ x8,
    const float* __restrict__ vtf,
    float* __restrict__ als, float* __restrict__ ald){
  int n = blockIdx.x * 4 + (threadIdx.x >> 6);       // 100000 exact
  int lane = threadIdx.x & 63;
  int j = lane & 15, q = lane >> 4;
  const int4* xp = (const int4*)(x8 + (size_t)n * DIM + q * 64);
  const float4* vp = (const float4*)(vtf + j * 256 + q * 64);
  f32x2 s2 = {0.f, 0.f};
  #pragma unroll
  for (int c = 0; c < 4; ++c){
    int4 xx = xp[c];
    int dws[4] = {xx.x, xx.y, xx.z, xx.w};
    #pragma unroll
    for (int m = 0; m < 4; ++m){
      float4 vv = vp[c * 4 + m];
      f32x2 lo = __builtin_amdgcn_cvt_pk_f32_fp8(dws[m], false);
      f32x2 hi = __builtin_amdgcn_cvt_pk_f32_fp8(dws[m], true);
      f32x2 v0 = {vv.x, vv.y}, v1 = {vv.z, vv.w};
      s2 = pkfma(lo, v0, s2);
      s2 = pkfma(hi, v1, s2);
    }
  }
  float s = s2[0] + s2[1];
  s += __shfl_xor(s, 16, 64);
  s += __shfl_xor(s, 32, 64);
  if (lane < 16){
    if (j < 8) als[(size_t)n * 8 + j] = s;
    else       ald[(size_t)n * 8 + (j - 8)] = s;
  }
}

// ---- aggregation over fp8 x: z8[n, h*256+d] = fp8( (1/den_h) * sum_e w_he * x8[src_e, d] )
// one wave per node; lane = (h = lane&7, dg = lane>>3 owning dims dg*32..+31)
// fp8 unpack via cvt_pk + packed dual-FP32 FMA; 2-edge software pipeline.
__global__ void __launch_bounds__(256) k_aggregate_x8(const unsigned char* __restrict__ x8,
    const float* __restrict__ als, const float* __restrict__ ald,
    const int* __restrict__ rp, const int* __restrict__ col,
    unsigned char* __restrict__ z8){
  int n = blockIdx.x * 4 + (threadIdx.x >> 6);       // 100000 exact
  int lane = threadIdx.x & 63;
  int h = lane & 7, dg = lane >> 3;
  int start = rp[n], end = rp[n + 1];
  if (start < 0) start = 0;
  if (end > NNZT) end = NNZT;
  if (end < start) end = start;
  float aldv = ald[(size_t)n * 8 + h];
  const unsigned char* xbase = x8 + dg * 32;

  float den = 0.f;
  f32x2 acc2[16];
  #pragma unroll
  for (int i = 0; i < 16; ++i) acc2[i] = (f32x2){0.f, 0.f};

  int e = start;
  if ((end - start) & 1){                            // peel one edge if odd count
    int src = col[e];
    if ((unsigned)src >= NN) src = n;
    const int4* xp = (const int4*)(xbase + (size_t)src * DIM);
    int4 a0 = xp[0], a1 = xp[1];
    float w = __expf(lrelu(als[(size_t)src * 8 + h] + aldv));
    den += w;
    f32x2 w2 = {w, w};
    acc32fp8(a0, a1, w2, acc2);
    ++e;
  }
  for (; e < end; e += 2){
    int s0 = col[e], s1 = col[e + 1];
    if ((unsigned)s0 >= NN) s0 = n;
    if ((unsigned)s1 >= NN) s1 = n;
    const int4* xp0 = (const int4*)(xbase + (size_t)s0 * DIM);
    const int4* xp1 = (const int4*)(xbase + (size_t)s1 * DIM);
    int4 a0 = xp0[0], a1 = xp0[1];
    int4 b0 = xp1[0], b1 = xp1[1];
    float al0 = als[(size_t)s0 * 8 + h];
    float al1 = als[(size_t)s1 * 8 + h];
    float w0 = __expf(lrelu(al0 + aldv));
    float w1 = __expf(lrelu(al1 + aldv));
    den += w0 + w1;
    f32x2 w20 = {w0, w0}, w21 = {w1, w1};
    acc32fp8(a0, a1, w20, acc2);
    acc32fp8(b0, b1, w21, acc2);
  }

  float r = 1.0f / den;
  unsigned pk[8];
  #pragma unroll
  for (int q = 0; q < 8; ++q){
    float a0 = acc2[2*q][0] * r,   a1 = acc2[2*q][1] * r;
    float a2 = acc2[2*q+1][0] * r, a3 = acc2[2*q+1][1] * r;
    int lo = __builtin_amdgcn_cvt_pk_fp8_f32(a0, a1, 0, false);
    pk[q] = (unsigned)__builtin_amdgcn_cvt_pk_fp8_f32(a2, a3, lo, true);
  }
  unsigned char* zp = z8 + (size_t)n * WCOLS + h * 256 + dg * 32;
  ((uint4*)zp)[0] = make_uint4(pk[0], pk[1], pk[2], pk[3]);
  ((uint4*)zp)[1] = make_uint4(pk[4], pk[5], pk[6], pk[7]);
}

// ---- big GEMM: out[n,j] = sum_k z[n,k] * bt[j,k]; epilogue P/Q (+relu -> fp8 x8) ----
// EXACT r7-proven loop structure (loads at loop top; no stage-ahead).
// 512 threads = 8 waves (2 row x 4 col), BM=128, BN=256, BK=64.
// A staged fp8 -> bf16 in registers, ds_write_b128 with XOR swizzle
// (physical 16B-block = logical_blk ^ (row & 7)) on BOTH write and read.
__global__ void __launch_bounds__(512) k_gemm2(const unsigned char* __restrict__ z8,
    const unsigned short* __restrict__ bt,
    const float* __restrict__ Pb, const float* __restrict__ Qb,
    unsigned char* __restrict__ x8out, float* __restrict__ fout, int last){
  __shared__ __align__(16) unsigned short sA[128 * 64];   // 16 KB
  __shared__ __align__(16) unsigned short sB[256 * 64];   // 32 KB
  int tid = threadIdx.x;
  int w = tid >> 6, lane = tid & 63;
  int wr = w >> 2, wc = w & 3;
  int ri = lane & 15, kg = lane >> 4;
  int m0 = blockIdx.x * 128;

  // A staging: row = tid>>2 (0..127), kq = tid&3 -> 16 fp8 bytes
  int rowA = tid >> 2, kqA = tid & 3;
  int rA = imin(m0 + rowA, NN - 1);
  const unsigned char* zrow = z8 + (size_t)rA * WCOLS + kqA * 16;
  int sAoff0 = rowA * 64 + (((kqA * 2)     ^ (rowA & 7)) * 8);
  int sAoff1 = rowA * 64 + (((kqA * 2 + 1) ^ (rowA & 7)) * 8);

  // B staging: 4 units; row = u>>3 (0..255), lb = u&7 (16B = 8 bf16)
  int rB[4], sBoff[4];
  #pragma unroll
  for (int p = 0; p < 4; ++p){
    int u = tid + p * 512;
    int row = u >> 3, lb = u & 7;
    rB[p] = row;
    sBoff[p] = row * 64 + ((lb ^ (row & 7)) * 8);
  }
  int lbB = tid & 7;

  f32x4 acc[4][4];
  #pragma unroll
  for (int i = 0; i < 4; ++i)
    #pragma unroll
    for (int j = 0; j < 4; ++j) acc[i][j] = (f32x4){0.f, 0.f, 0.f, 0.f};

  for (int t = 0; t < 32; ++t){
    int kbase = t * 64;
    uint4 raw = *(const uint4*)(zrow + kbase);
    int4 vb[4];
    #pragma unroll
    for (int p = 0; p < 4; ++p)
      vb[p] = *(const int4*)(bt + (size_t)rB[p] * WCOLS + kbase + lbB * 8);
    int4 cl, ch;
    fp8dw_to_bf16x4((int)raw.x, cl.x, cl.y);
    fp8dw_to_bf16x4((int)raw.y, cl.z, cl.w);
    fp8dw_to_bf16x4((int)raw.z, ch.x, ch.y);
    fp8dw_to_bf16x4((int)raw.w, ch.z, ch.w);
    *(int4*)(sA + sAoff0) = cl;
    *(int4*)(sA + sAoff1) = ch;
    #pragma unroll
    for (int p = 0; p < 4; ++p) *(int4*)(sB + sBoff[p]) = vb[p];
    __syncthreads();
    #pragma unroll
    for (int ks = 0; ks < 2; ++ks){
      v8bf a[4], b[4];
      #pragma unroll
      for (int ai = 0; ai < 4; ++ai){
        int r = wr * 64 + ai * 16 + ri;
        int pb = (ks * 4 + kg) ^ (r & 7);
        a[ai] = *(const v8bf*)((const unsigned char*)sA + r * 128 + pb * 16);
      }
      #pragma unroll
      for (int bj = 0; bj < 4; ++bj){
        int r = wc * 64 + bj * 16 + ri;
        int pb = (ks * 4 + kg) ^ (r & 7);
        b[bj] = *(const v8bf*)((const unsigned char*)sB + r * 128 + pb * 16);
      }
      #pragma unroll
      for (int ai = 0; ai < 4; ++ai)
        #pragma unroll
        for (int bj = 0; bj < 4; ++bj)
          acc[ai][bj] = __builtin_amdgcn_mfma_f32_16x16x32_bf16(a[ai], b[bj], acc[ai][bj], 0, 0, 0);
    }
    __syncthreads();
  }

  // epilogue: C[m0 + wr*64 + ai*16 + kg*4 + r][wc*64 + bj*16 + ri]
  #pragma unroll
  for (int bj = 0; bj < 4; ++bj){
    int colj = wc * 64 + bj * 16 + ri;
    float p = Pb[colj], q = Qb[colj];
    #pragma unroll
    for (int ai = 0; ai < 4; ++ai){
      #pragma unroll
      for (int r = 0; r < 4; ++r){
        int row = m0 + wr * 64 + ai * 16 + kg * 4 + r;
        if (row < NN){
          float v = acc[ai][bj][r] * p + q;
          if (!last){
            v = fmaxf(v, 0.f);
            x8out[(size_t)row * DIM + colj] = f2fp8(v);
          } else {
            fout[(size_t)row * DIM + colj] = v;
          }
        }
      }
    }
  }
}

// ---- doc GEMM: [64,3072]@[3072,256] fp32, one block per row ----
__global__ void __launch_bounds__(256) k_doc(const float* __restrict__ dd,
    const float* __restrict__ dw, const float* __restrict__ db, float* __restrict__ out){
  int r = blockIdx.x;                 // 64 rows
  int j = threadIdx.x;                // 256 cols
  const float* drow = dd + (size_t)r * 3072;
  float acc = db[j];
  #pragma unroll 4
  for (int k = 0; k < 3072; ++k)
    acc = fmaf(drow[k], dw[(size_t)k * 256 + j], acc);
  out[(size_t)NN * DIM + (size_t)r * 256 + j] = acc;
}

extern "C" void kernel_launch(void* const* d_in, const int* in_sizes, int n_in,
                              void* d_out, int out_size, void* d_ws, size_t ws_size,
                              hipStream_t stream) {
  (void)in_sizes; (void)n_in; (void)out_size; (void)ws_size;
  const float* x      = (const float*)d_in[0];
  const int*   ei     = (const int*)d_in[1];
  const float* doc    = (const float*)d_in[2];
  const float* W[3]   = {(const float*)d_in[3], (const float*)d_in[7], (const float*)d_in[11]};
  const float* as_[3] = {(const float*)d_in[4], (const float*)d_in[8], (const float*)d_in[12]};
  const float* ad_[3] = {(const float*)d_in[5], (const float*)d_in[9], (const float*)d_in[13]};
  const float* b_[3]  = {(const float*)d_in[6], (const float*)d_in[10], (const float*)d_in[14]};
  const float* bng[2] = {(const float*)d_in[15], (const float*)d_in[19]};
  const float* bnb[2] = {(const float*)d_in[16], (const float*)d_in[20]};
  const float* bnm[2] = {(const float*)d_in[17], (const float*)d_in[21]};
  const float* bnv[2] = {(const float*)d_in[18], (const float*)d_in[22]};
  const float* docW   = (const float*)d_in[23];
  const float* docB   = (const float*)d_in[24];
  float* out = (float*)d_out;

  char* ws = (char*)d_ws;
  // Total footprint 254,396,992 B — inside the twice-proven 279,947,840 bound.
  unsigned char*  x8   = (unsigned char*)(ws + 0);             //  25,600,000
  unsigned char*  z8   = (unsigned char*)(ws + 25600000);      // 204,800,000
  float* als           = (float*)(ws + 230400000);             //   3,200,000
  float* ald           = (float*)(ws + 233600000);             //   3,200,000
  unsigned short* bt   = (unsigned short*)(ws + 236800000);    //   3,145,728 (3 x 1 MiB)
  int* rp              = (int*)(ws + 239945728);               //     400,064
  int* deg             = (int*)(ws + 240345792);               //     400,000
  int* cur             = (int*)(ws + 240745792);               //     400,000
  int* colb            = (int*)(ws + 241145792);               //  13,200,000
  float* vtf           = (float*)(ws + 254345792);             //      49,152 (3 x 16 KiB)
  float* Pb            = (float*)(ws + 254394944);             //       1,024
  float* Qb            = (float*)(ws + 254395968);             //       1,024 -> end 254,396,992

  // input prep
  k_cast_x8<<<25000, 256, 0, stream>>>(x, x8);
  for (int L = 0; L < 3; ++L){
    k_make_waggt<<<2048, 256, 0, stream>>>(W[L], bt + (size_t)L * 524288);
    k_make_vtf<<<8, 256, 0, stream>>>(W[L], as_[L], ad_[L], vtf + (size_t)L * 4096);
  }

  // CSR (shared by all 3 layers); deg/cur strictly distinct buffers
  k_zero_col<<<12891, 256, 0, stream>>>(colb);
  k_deg_init<<<391, 256, 0, stream>>>(deg);
  k_hist<<<12500, 256, 0, stream>>>(ei, deg);
  k_scan<<<1, 1024, 0, stream>>>(deg, rp, cur);
  k_fill_self<<<391, 256, 0, stream>>>(cur, colb);
  k_fill_edge<<<12500, 256, 0, stream>>>(ei, cur, colb);

  // layers
  for (int L = 0; L < 3; ++L){
    int has_bn = (L < 2) ? 1 : 0;
    k_pq<<<1, 256, 0, stream>>>(has_bn ? bng[L] : nullptr, has_bn ? bnb[L] : nullptr,
                                has_bn ? bnm[L] : nullptr, has_bn ? bnv[L] : nullptr,
                                b_[L], has_bn, Pb, Qb);
    k_alpha_v<<<25000, 256, 0, stream>>>(x8, vtf + (size_t)L * 4096, als, ald);
    k_aggregate_x8<<<25000, 256, 0, stream>>>(x8, als, ald, rp, colb, z8);
    k_gemm2<<<782, 512, 0, stream>>>(z8, bt + (size_t)L * 524288, Pb, Qb,
                                     x8, out, (L == 2) ? 1 : 0);
  }

  // doc branch
  k_doc<<<64, 256, 0, stream>>>(doc, docW, docB, out);
}